// Round 7
// baseline (646.369 us; speedup 1.0000x reference)
//
#include <hip/hip_runtime.h>
#include <math.h>

#define N_NODES_C 50000
#define N_EDGES_C 1600000
#define N_GRAPHS_C 2048
#define NBUK 391  // ceil(50000 / 128) buckets of 128 dst nodes

typedef short short8 __attribute__((ext_vector_type(8)));
typedef float f32x4 __attribute__((ext_vector_type(4)));

static __device__ __forceinline__ int lowerBound(const int* __restrict__ a, int n, int v) {
    int lo = 0, hi = n;
    while (lo < hi) {
        int mid = (lo + hi) >> 1;
        if (a[mid] < v) lo = mid + 1; else hi = mid;
    }
    return lo;
}

// bf16 helpers: round-to-nearest-even pack, and unpack of a 2x-bf16 word
static __device__ __forceinline__ unsigned short f2bf(float f) {
    unsigned u = __float_as_uint(f);
    return (unsigned short)((u + 0x7FFFu + ((u >> 16) & 1u)) >> 16);
}
static __device__ __forceinline__ float blo(unsigned v) { return __uint_as_float(v << 16); }
static __device__ __forceinline__ float bhi(unsigned v) { return __uint_as_float(v & 0xFFFF0000u); }

// ---------------- CSR build v2: bucketed counting sort (dense writes only) ----------------

__global__ __launch_bounds__(256) void bucket_count_kernel(
    const int* __restrict__ ei, int* __restrict__ bucketCnt, int E) {
    __shared__ int lh[NBUK];
    int t = threadIdx.x;
    for (int i = t; i < NBUK; i += 256) lh[i] = 0;
    __syncthreads();
    for (int e = blockIdx.x * blockDim.x + t; e < E; e += gridDim.x * blockDim.x)
        atomicAdd(&lh[((unsigned)ei[E + e]) >> 7], 1);
    __syncthreads();
    for (int i = t; i < NBUK; i += 256) {
        int c = lh[i];
        if (c) atomicAdd(&bucketCnt[i], c);
    }
}

__global__ __launch_bounds__(512) void bucket_scan_kernel(
    const int* __restrict__ bucketCnt, int* __restrict__ bucketPtr, int* __restrict__ bucketCur) {
    __shared__ int v[512];
    int t = threadIdx.x;
    int x = (t < NBUK) ? bucketCnt[t] : 0;
    v[t] = x;
    __syncthreads();
    for (int off = 1; off < 512; off <<= 1) {
        int y = (t >= off) ? v[t - off] : 0;
        __syncthreads();
        v[t] += y;
        __syncthreads();
    }
    int excl = v[t] - x;
    if (t <= NBUK) bucketPtr[t] = excl;
    if (t < NBUK) bucketCur[t] = excl;
}

__global__ __launch_bounds__(256) void bucket_scatter_kernel(
    const int* __restrict__ ei, int* __restrict__ bucketCur,
    unsigned* __restrict__ bucketBuf, int E) {
    __shared__ int lh[NBUK];
    int t = threadIdx.x;
    for (int i = t; i < NBUK; i += 256) lh[i] = 0;
    __syncthreads();
    int per = (E + gridDim.x - 1) / gridDim.x;
    int beg = blockIdx.x * per;
    int end = min(beg + per, E);
    for (int e = beg + t; e < end; e += 256)
        atomicAdd(&lh[((unsigned)ei[E + e]) >> 7], 1);
    __syncthreads();
    for (int i = t; i < NBUK; i += 256) {
        int c = lh[i];
        lh[i] = c ? atomicAdd(&bucketCur[i], c) : 0;
    }
    __syncthreads();
    for (int e = beg + t; e < end; e += 256) {
        int s = ei[e], d = ei[E + e];
        int pos = atomicAdd(&lh[((unsigned)d) >> 7], 1);
        bucketBuf[pos] = (unsigned)s | ((unsigned)(d & 127) << 16);
    }
}

__global__ __launch_bounds__(256) void csr_finalize_kernel(
    const int* __restrict__ bucketPtr, const unsigned* __restrict__ bucketBuf,
    int* __restrict__ rowptr, int* __restrict__ csr, int n) {
    __shared__ int hist[128], sc[128], cur[128];
    int b = blockIdx.x, t = threadIdx.x;
    int base = b << 7;
    int nb = min(128, n - base);
    if (t < 128) hist[t] = (t < nb) ? 1 : 0;
    __syncthreads();
    int ebeg = bucketPtr[b], eend = bucketPtr[b + 1];
    for (int i = ebeg + t; i < eend; i += 256)
        atomicAdd(&hist[bucketBuf[i] >> 16], 1);
    __syncthreads();
    if (t < 128) sc[t] = hist[t];
    __syncthreads();
    for (int off = 1; off < 128; off <<= 1) {
        int y = 0;
        if (t < 128 && t >= off) y = sc[t - off];
        __syncthreads();
        if (t < 128) sc[t] += y;
        __syncthreads();
    }
    int csrStart = ebeg + base;
    if (t < nb) {
        int rpos = csrStart + sc[t] - hist[t];
        rowptr[base + t] = rpos;
        csr[rpos] = base + t;
        cur[t] = rpos + 1;
    }
    if (b == 0 && t == 0) rowptr[n] = bucketPtr[NBUK] + n;
    __syncthreads();
    for (int i = ebeg + t; i < eend; i += 256) {
        unsigned v = bucketBuf[i];
        int pos = atomicAdd(&cur[v >> 16], 1);
        csr[pos] = (int)(v & 0xFFFFu);
    }
}

// ---------------- weight convert + transpose: Wt[c][k] = bf16(W[k][c]) ----------------

__global__ __launch_bounds__(256) void wt_conv_kernel(
    const float* __restrict__ W, unsigned short* __restrict__ Wt, int K, int C) {
    int i = blockIdx.x * 256 + threadIdx.x;
    if (i < K * C) {
        int c = i / K, k = i - c * K;
        Wt[i] = f2bf(W[(size_t)k * C + c]);
    }
}

// ---------------- MFMA GEMM: h = x@W (bf16 in, fp32 acc), fused als/ald ----------------

template<int DOUT>
__global__ __launch_bounds__(256) void gemm_mfma(
    const unsigned short* __restrict__ xb,   // [n][128] bf16
    const unsigned short* __restrict__ Wt,   // [DOUT][128] bf16 (transposed W)
    const float* __restrict__ avs, const float* __restrict__ avd,
    unsigned* __restrict__ hb,               // [n][DOUT/2] packed bf16x2
    float* __restrict__ als, float* __restrict__ ald, int n) {
    constexpr int NT = DOUT / 16;
    int w = threadIdx.x >> 6, l = threadIdx.x & 63;
    int lc = l & 15, lg = l >> 4;
    int n0 = blockIdx.x * 64 + w * 16;
    int nrow = min(n0 + lc, n - 1);
    f32x4 acc[NT];
#pragma unroll
    for (int ct = 0; ct < NT; ct++) acc[ct] = (f32x4){0.f, 0.f, 0.f, 0.f};
    const unsigned short* xrow = xb + (size_t)nrow * 128 + lg * 8;
#pragma unroll
    for (int kb = 0; kb < 128; kb += 32) {
        short8 xf = *(const short8*)(xrow + kb);
#pragma unroll
        for (int ct = 0; ct < NT; ct++) {
            short8 wf = *(const short8*)(Wt + (size_t)(ct * 16 + lc) * 128 + kb + lg * 8);
            acc[ct] = __builtin_amdgcn_mfma_f32_16x16x32_bf16(wf, xf, acc[ct], 0, 0, 0);
        }
    }
    int node = n0 + lc;
    bool ok = node < n;
    float ps = 0.f, pd = 0.f;
#pragma unroll
    for (int ct = 0; ct < NT; ct++) {
        int cb = ct * 16 + lg * 4;
#pragma unroll
        for (int j = 0; j < 4; j++) { ps += acc[ct][j] * avs[cb + j]; pd += acc[ct][j] * avd[cb + j]; }
        if (ok) {
            uint2 v;
            v.x = (unsigned)f2bf(acc[ct][0]) | ((unsigned)f2bf(acc[ct][1]) << 16);
            v.y = (unsigned)f2bf(acc[ct][2]) | ((unsigned)f2bf(acc[ct][3]) << 16);
            *(uint2*)&hb[(size_t)node * (DOUT / 2) + ct * 8 + lg * 2] = v;
        }
    }
    ps += __shfl_xor(ps, 16); ps += __shfl_xor(ps, 32);
    pd += __shfl_xor(pd, 16); pd += __shfl_xor(pd, 32);
    if (ok && lg == 0) { als[node] = ps; ald[node] = pd; }
}

// ---------------- layer 1: DIN=7 -> DOUT=128 (fp32 math, bf16 h out) ----------------

__global__ __launch_bounds__(256) void linear_att_l1(
    const float* __restrict__ x, const float* __restrict__ W,
    const float* __restrict__ avs, const float* __restrict__ avd,
    unsigned* __restrict__ hb, float* __restrict__ als, float* __restrict__ ald, int n) {
    __shared__ float Wl[7 * 128];
    __shared__ float xsh[32][8];
    int tid = threadIdx.x;
    for (int i = tid; i < 7 * 128; i += 256) Wl[i] = W[i];
    int nodeBase = blockIdx.x * 32;
    if (tid < 224) {
        int nd = tid / 7, k = tid % 7;
        int g = min(nodeBase + nd, n - 1);
        xsh[nd][k] = x[(size_t)g * 7 + k];
    }
    __syncthreads();
    int nl = tid >> 3;
    int og = (tid & 7) * 16;
    int g = nodeBase + nl;
    float acc[16];
#pragma unroll
    for (int o = 0; o < 16; o++) acc[o] = 0.f;
#pragma unroll
    for (int k = 0; k < 7; k++) {
        float xv = xsh[nl][k];
#pragma unroll
        for (int o = 0; o < 16; o++) acc[o] += xv * Wl[k * 128 + og + o];
    }
    if (g < n) {
        unsigned pk[8];
#pragma unroll
        for (int o = 0; o < 16; o += 2)
            pk[o >> 1] = (unsigned)f2bf(acc[o]) | ((unsigned)f2bf(acc[o + 1]) << 16);
        uint4 v0, v1;
        v0.x = pk[0]; v0.y = pk[1]; v0.z = pk[2]; v0.w = pk[3];
        v1.x = pk[4]; v1.y = pk[5]; v1.z = pk[6]; v1.w = pk[7];
        *(uint4*)&hb[(size_t)g * 64 + (og >> 1)] = v0;
        *(uint4*)&hb[(size_t)g * 64 + (og >> 1) + 4] = v1;
        float ps = 0.f, pd = 0.f;
#pragma unroll
        for (int o = 0; o < 16; o++) { ps += acc[o] * avs[og + o]; pd += acc[o] * avd[og + o]; }
#pragma unroll
        for (int off = 1; off < 8; off <<= 1) { ps += __shfl_xor(ps, off); pd += __shfl_xor(pd, off); }
        if ((tid & 7) == 0) { als[g] = ps; ald[g] = pd; }
    }
}

// ---------------- softmax-weighted aggregation v4 ----------------
// One wave per node, zero LDS/barriers. Lane = (edge-of-group, 16B slice of h row).
// DOUT=128: 4 edges/group, uint4 loads; DOUT=64: 8 edges/group.
// Per-slot (src,alpha) broadcast from pass-A registers via shfl; 2-stage pipelined loads.

template<int DOUT, bool OBF>
__global__ __launch_bounds__(64) void gat_agg4(
    const int* __restrict__ rowptr, const int* __restrict__ csr,
    const float* __restrict__ als, const float* __restrict__ ald,
    const unsigned char* __restrict__ hbB, const float* __restrict__ bias,
    float* __restrict__ xout, int n) {
    constexpr int ROWB = DOUT * 2;   // h row bytes
    constexpr int LPE  = ROWB / 16;  // lanes per edge (16-B slices): 16 or 8
    constexpr int EPG  = 64 / LPE;   // edges per group: 4 or 8
    int lane = threadIdx.x;
    int node = blockIdx.x;
    if (node >= n) return;
    int beg = rowptr[node], end = rowptr[node + 1];
    int deg = end - beg;
    float adi = ald[node];

    // ---- pass A: softmax stats (max-butterfly, exp, sum-butterfly) ----
    float e0 = -INFINITY, mloc = -INFINITY;
    int src0 = node;
    {
        int idx = beg + lane;
        if (idx < end) {
            int src = csr[idx];
            float e = als[src] + adi;
            e = (e > 0.f) ? e : 0.2f * e;   // leaky_relu 0.2
            e0 = e; mloc = e; src0 = src;
            for (idx += 64; idx < end; idx += 64) {   // rare deg>64
                src = csr[idx];
                e = als[src] + adi;
                e = (e > 0.f) ? e : 0.2f * e;
                mloc = fmaxf(mloc, e);
            }
        }
    }
#pragma unroll
    for (int o = 1; o < 64; o <<= 1) mloc = fmaxf(mloc, __shfl_xor(mloc, o));
    float m = mloc;
    float p0 = expf(e0 - m);   // 0 for idle lanes (e0 = -inf)
    float sloc = p0;
    if (deg > 64) {
        for (int idx = beg + lane + 64; idx < end; idx += 64) {
            int src = csr[idx];
            float e = als[src] + adi;
            e = (e > 0.f) ? e : 0.2f * e;
            sloc += expf(e - m);
        }
    }
    float s = sloc;
#pragma unroll
    for (int o = 1; o < 64; o <<= 1) s += __shfl_xor(s, o);
    float inv_den = 1.f / s;

    // ---- pass B: pipelined 16-B slice gather ----
    int eSel = lane / LPE;
    const unsigned char* hbs = hbB + (lane % LPE) * 16;
    unsigned ownOff = (unsigned)node * ROWB;

    float acc[8];
#pragma unroll
    for (int i = 0; i < 8; i++) acc[i] = 0.f;

    for (int win = 0; win < deg; win += 64) {
        float alphaL; unsigned offL;
        if (win == 0) {
            alphaL = p0 * inv_den;
            offL = (beg + lane < end) ? (unsigned)src0 * ROWB : ownOff;
        } else {   // rare deg>64 windows
            int idx = beg + win + lane;
            if (idx < end) {
                int src = csr[idx];
                float e = als[src] + adi;
                e = (e > 0.f) ? e : 0.2f * e;
                alphaL = expf(e - m) * inv_den;
                offL = (unsigned)src * ROWB;
            } else { alphaL = 0.f; offL = ownOff; }
        }
        int limW = min(deg - win, 64);
        int nG = (limW + EPG - 1) / EPG;
        unsigned off_c = (unsigned)__shfl((int)offL, eSel);
        float a_c = __shfl(alphaL, eSel);
        uint4 v_c = *(const uint4*)(hbs + off_c);
        for (int g = 1; g < nG; g++) {
            int slot = g * EPG + eSel;
            unsigned off_n = (unsigned)__shfl((int)offL, slot);
            float a_n = __shfl(alphaL, slot);
            uint4 v_n = *(const uint4*)(hbs + off_n);   // issued before consuming v_c
            acc[0] += a_c * blo(v_c.x); acc[1] += a_c * bhi(v_c.x);
            acc[2] += a_c * blo(v_c.y); acc[3] += a_c * bhi(v_c.y);
            acc[4] += a_c * blo(v_c.z); acc[5] += a_c * bhi(v_c.z);
            acc[6] += a_c * blo(v_c.w); acc[7] += a_c * bhi(v_c.w);
            off_c = off_n; a_c = a_n; v_c = v_n;
        }
        acc[0] += a_c * blo(v_c.x); acc[1] += a_c * bhi(v_c.x);
        acc[2] += a_c * blo(v_c.y); acc[3] += a_c * bhi(v_c.y);
        acc[4] += a_c * blo(v_c.z); acc[5] += a_c * bhi(v_c.z);
        acc[6] += a_c * blo(v_c.w); acc[7] += a_c * bhi(v_c.w);
    }

    // reduce edge-substreams (lanes with same slice index)
#pragma unroll
    for (int o = LPE; o < 64; o <<= 1) {
#pragma unroll
        for (int i = 0; i < 8; i++) acc[i] += __shfl_xor(acc[i], o);
    }

    if (lane < LPE) {
        int c0 = lane * 8;
        float v[8];
#pragma unroll
        for (int i = 0; i < 8; i++) {
            float t = acc[i] + bias[c0 + i];
            v[i] = (t > 0.f) ? t : expm1f(t);   // jax.nn.elu
        }
        if constexpr (OBF) {
            uint4 pk;
            pk.x = (unsigned)f2bf(v[0]) | ((unsigned)f2bf(v[1]) << 16);
            pk.y = (unsigned)f2bf(v[2]) | ((unsigned)f2bf(v[3]) << 16);
            pk.z = (unsigned)f2bf(v[4]) | ((unsigned)f2bf(v[5]) << 16);
            pk.w = (unsigned)f2bf(v[6]) | ((unsigned)f2bf(v[7]) << 16);
            *(uint4*)((unsigned*)xout + (size_t)node * (DOUT / 2) + lane * 4) = pk;
        } else {
            float4 f0, f1;
            f0.x = v[0]; f0.y = v[1]; f0.z = v[2]; f0.w = v[3];
            f1.x = v[4]; f1.y = v[5]; f1.z = v[6]; f1.w = v[7];
            *(float4*)&xout[(size_t)node * DOUT + c0] = f0;
            *(float4*)&xout[(size_t)node * DOUT + c0 + 4] = f1;
        }
    }
}

// ---------------- pool (mean over batch segment) + concat + final linear ----------------

__global__ __launch_bounds__(64) void pool_final_kernel(
    const float* __restrict__ x, const int* __restrict__ batch,
    const float* __restrict__ xnorm, const float* __restrict__ linW,
    const float* __restrict__ linb, float* __restrict__ out, int n) {
    int g = blockIdx.x, t = threadIdx.x;
    int lo = lowerBound(batch, n, g);
    int hi = lowerBound(batch, n, g + 1);
    float sum = 0.f;
    for (int i = lo; i < hi; i++) sum += x[(size_t)i * 64 + t];
    float cnt = (float)(hi - lo);
    float mean = sum / fmaxf(cnt, 1.f);
    __shared__ float gv[80];
    gv[t] = mean;
    if (t < 16) gv[64 + t] = xnorm[g * 16 + t];
    __syncthreads();
    float acc = linb[t];
#pragma unroll
    for (int k = 0; k < 80; k++) acc += gv[k] * linW[k * 64 + t];
    out[(size_t)g * 64 + t] = acc;
}

// ---------------- launch ----------------

extern "C" void kernel_launch(void* const* d_in, const int* in_sizes, int n_in,
                              void* d_out, int out_size, void* d_ws, size_t ws_size,
                              hipStream_t stream) {
    const float* x1  = (const float*)d_in[0];
    const float* x2  = (const float*)d_in[1];
    const int*   ei1 = (const int*)d_in[2];
    const int*   ei2 = (const int*)d_in[3];
    const int*   batch = (const int*)d_in[4];
    const float* xn1 = (const float*)d_in[6];
    const float* xn2 = (const float*)d_in[7];
    const float* W1 = (const float*)d_in[8];
    const float* as1 = (const float*)d_in[9];
    const float* ad1 = (const float*)d_in[10];
    const float* b1 = (const float*)d_in[11];
    const float* W2 = (const float*)d_in[12];
    const float* as2 = (const float*)d_in[13];
    const float* ad2 = (const float*)d_in[14];
    const float* b2 = (const float*)d_in[15];
    const float* W3 = (const float*)d_in[16];
    const float* as3 = (const float*)d_in[17];
    const float* ad3 = (const float*)d_in[18];
    const float* b3 = (const float*)d_in[19];
    const float* linW = (const float*)d_in[20];
    const float* linb = (const float*)d_in[21];
    float* out = (float*)d_out;

    char* ws = (char*)d_ws;
    size_t off = 0;
    auto alloc = [&](size_t bytes) -> void* {
        void* p = ws + off;
        off += (bytes + 255) & ~(size_t)255;
        return p;
    };
    int* rowptr    = (int*)alloc((N_NODES_C + 1) * sizeof(int));
    int* csr       = (int*)alloc((size_t)(N_EDGES_C + N_NODES_C) * sizeof(int));
    float* als     = (float*)alloc(N_NODES_C * sizeof(float));
    float* ald     = (float*)alloc(N_NODES_C * sizeof(float));
    int* bucketCnt = (int*)alloc(NBUK * sizeof(int));
    int* bucketPtr = (int*)alloc((NBUK + 1) * sizeof(int));
    int* bucketCur = (int*)alloc(NBUK * sizeof(int));
    unsigned short* Wt2 = (unsigned short*)alloc(128 * 128 * sizeof(unsigned short));
    unsigned short* Wt3 = (unsigned short*)alloc(64 * 128 * sizeof(unsigned short));
    float* bufX    = (float*)alloc((size_t)N_NODES_C * 64 * sizeof(float));        // fp32 final agg out
    unsigned* hb   = (unsigned*)alloc((size_t)N_NODES_C * 64 * sizeof(unsigned));  // bf16x2 h
    unsigned short* xbb = (unsigned short*)alloc((size_t)N_NODES_C * 128 * sizeof(unsigned short)); // bf16 x
    unsigned* bucketBuf = (unsigned*)bufX;  // aliased: lifetimes don't overlap
    (void)ws_size; (void)in_sizes; (void)n_in; (void)out_size;

    const int GEMM_GRID = (N_NODES_C + 63) / 64;

    // one-time: W2/W3 -> bf16 transposed
    wt_conv_kernel<<<(128 * 128 + 255) / 256, 256, 0, stream>>>(W2, Wt2, 128, 128);
    wt_conv_kernel<<<(128 * 64 + 255) / 256, 256, 0, stream>>>(W3, Wt3, 128, 64);

    for (int br = 0; br < 2; br++) {
        const float* x  = (br == 0) ? x1 : x2;
        const int*   ei = (br == 0) ? ei1 : ei2;
        const float* xn = (br == 0) ? xn1 : xn2;
        float* o = out + (size_t)br * N_GRAPHS_C * 64;

        // CSR build (dst-sorted adjacency incl. self loops, dense writes)
        hipMemsetAsync(bucketCnt, 0, NBUK * sizeof(int), stream);
        bucket_count_kernel<<<1024, 256, 0, stream>>>(ei, bucketCnt, N_EDGES_C);
        bucket_scan_kernel<<<1, 512, 0, stream>>>(bucketCnt, bucketPtr, bucketCur);
        bucket_scatter_kernel<<<256, 256, 0, stream>>>(ei, bucketCur, bucketBuf, N_EDGES_C);
        csr_finalize_kernel<<<NBUK, 256, 0, stream>>>(bucketPtr, bucketBuf, rowptr, csr, N_NODES_C);

        // Layer 1: 7 -> 128
        linear_att_l1<<<(N_NODES_C + 31) / 32, 256, 0, stream>>>(x, W1, as1, ad1, hb, als, ald, N_NODES_C);
        gat_agg4<128, true><<<N_NODES_C, 64, 0, stream>>>(rowptr, csr, als, ald, (const unsigned char*)hb, b1, (float*)xbb, N_NODES_C);
        // Layer 2: 128 -> 128 (MFMA)
        gemm_mfma<128><<<GEMM_GRID, 256, 0, stream>>>(xbb, Wt2, as2, ad2, hb, als, ald, N_NODES_C);
        gat_agg4<128, true><<<N_NODES_C, 64, 0, stream>>>(rowptr, csr, als, ald, (const unsigned char*)hb, b2, (float*)xbb, N_NODES_C);
        // Layer 3: 128 -> 64 (MFMA)
        gemm_mfma<64><<<GEMM_GRID, 256, 0, stream>>>(xbb, Wt3, as3, ad3, hb, als, ald, N_NODES_C);
        gat_agg4<64, false><<<N_NODES_C, 64, 0, stream>>>(rowptr, csr, als, ald, (const unsigned char*)hb, b3, bufX, N_NODES_C);

        // mean pool + concat + linear head
        pool_final_kernel<<<N_GRAPHS_C, 64, 0, stream>>>(bufX, batch, xn, linW, linb, o, N_NODES_C);
    }
}

// Round 8
// 628.487 us; speedup vs baseline: 1.0285x; 1.0285x over previous
//
#include <hip/hip_runtime.h>
#include <math.h>

#define N_NODES_C 50000
#define N_EDGES_C 1600000
#define N_GRAPHS_C 2048
#define NBUK 391  // ceil(50000 / 128) buckets of 128 dst nodes

typedef short short8 __attribute__((ext_vector_type(8)));
typedef float f32x4 __attribute__((ext_vector_type(4)));

static __device__ __forceinline__ int lowerBound(const int* __restrict__ a, int n, int v) {
    int lo = 0, hi = n;
    while (lo < hi) {
        int mid = (lo + hi) >> 1;
        if (a[mid] < v) lo = mid + 1; else hi = mid;
    }
    return lo;
}

// bf16 helpers: round-to-nearest-even pack, and unpack of a 2x-bf16 word
static __device__ __forceinline__ unsigned short f2bf(float f) {
    unsigned u = __float_as_uint(f);
    return (unsigned short)((u + 0x7FFFu + ((u >> 16) & 1u)) >> 16);
}
static __device__ __forceinline__ float blo(unsigned v) { return __uint_as_float(v << 16); }
static __device__ __forceinline__ float bhi(unsigned v) { return __uint_as_float(v & 0xFFFF0000u); }

// ---------------- CSR build v2: bucketed counting sort (dense writes only) ----------------

__global__ __launch_bounds__(256) void bucket_count_kernel(
    const int* __restrict__ ei, int* __restrict__ bucketCnt, int E) {
    __shared__ int lh[NBUK];
    int t = threadIdx.x;
    for (int i = t; i < NBUK; i += 256) lh[i] = 0;
    __syncthreads();
    for (int e = blockIdx.x * blockDim.x + t; e < E; e += gridDim.x * blockDim.x)
        atomicAdd(&lh[((unsigned)ei[E + e]) >> 7], 1);
    __syncthreads();
    for (int i = t; i < NBUK; i += 256) {
        int c = lh[i];
        if (c) atomicAdd(&bucketCnt[i], c);
    }
}

__global__ __launch_bounds__(512) void bucket_scan_kernel(
    const int* __restrict__ bucketCnt, int* __restrict__ bucketPtr, int* __restrict__ bucketCur) {
    __shared__ int v[512];
    int t = threadIdx.x;
    int x = (t < NBUK) ? bucketCnt[t] : 0;
    v[t] = x;
    __syncthreads();
    for (int off = 1; off < 512; off <<= 1) {
        int y = (t >= off) ? v[t - off] : 0;
        __syncthreads();
        v[t] += y;
        __syncthreads();
    }
    int excl = v[t] - x;
    if (t <= NBUK) bucketPtr[t] = excl;
    if (t < NBUK) bucketCur[t] = excl;
}

__global__ __launch_bounds__(256) void bucket_scatter_kernel(
    const int* __restrict__ ei, int* __restrict__ bucketCur,
    unsigned* __restrict__ bucketBuf, int E) {
    __shared__ int lh[NBUK];
    int t = threadIdx.x;
    for (int i = t; i < NBUK; i += 256) lh[i] = 0;
    __syncthreads();
    int per = (E + gridDim.x - 1) / gridDim.x;
    int beg = blockIdx.x * per;
    int end = min(beg + per, E);
    for (int e = beg + t; e < end; e += 256)
        atomicAdd(&lh[((unsigned)ei[E + e]) >> 7], 1);
    __syncthreads();
    for (int i = t; i < NBUK; i += 256) {
        int c = lh[i];
        lh[i] = c ? atomicAdd(&bucketCur[i], c) : 0;
    }
    __syncthreads();
    for (int e = beg + t; e < end; e += 256) {
        int s = ei[e], d = ei[E + e];
        int pos = atomicAdd(&lh[((unsigned)d) >> 7], 1);
        bucketBuf[pos] = (unsigned)s | ((unsigned)(d & 127) << 16);
    }
}

__global__ __launch_bounds__(256) void csr_finalize_kernel(
    const int* __restrict__ bucketPtr, const unsigned* __restrict__ bucketBuf,
    int* __restrict__ rowptr, int* __restrict__ csr, int n) {
    __shared__ int hist[128], sc[128], cur[128];
    int b = blockIdx.x, t = threadIdx.x;
    int base = b << 7;
    int nb = min(128, n - base);
    if (t < 128) hist[t] = (t < nb) ? 1 : 0;
    __syncthreads();
    int ebeg = bucketPtr[b], eend = bucketPtr[b + 1];
    for (int i = ebeg + t; i < eend; i += 256)
        atomicAdd(&hist[bucketBuf[i] >> 16], 1);
    __syncthreads();
    if (t < 128) sc[t] = hist[t];
    __syncthreads();
    for (int off = 1; off < 128; off <<= 1) {
        int y = 0;
        if (t < 128 && t >= off) y = sc[t - off];
        __syncthreads();
        if (t < 128) sc[t] += y;
        __syncthreads();
    }
    int csrStart = ebeg + base;
    if (t < nb) {
        int rpos = csrStart + sc[t] - hist[t];
        rowptr[base + t] = rpos;
        csr[rpos] = base + t;
        cur[t] = rpos + 1;
    }
    if (b == 0 && t == 0) rowptr[n] = bucketPtr[NBUK] + n;
    __syncthreads();
    for (int i = ebeg + t; i < eend; i += 256) {
        unsigned v = bucketBuf[i];
        int pos = atomicAdd(&cur[v >> 16], 1);
        csr[pos] = (int)(v & 0xFFFFu);
    }
}

// ---------------- weight convert + transpose: Wt[c][k] = bf16(W[k][c]) ----------------

__global__ __launch_bounds__(256) void wt_conv_kernel(
    const float* __restrict__ W, unsigned short* __restrict__ Wt, int K, int C) {
    int i = blockIdx.x * 256 + threadIdx.x;
    if (i < K * C) {
        int c = i / K, k = i - c * K;
        Wt[i] = f2bf(W[(size_t)k * C + c]);
    }
}

// ---------------- MFMA GEMM: h = x@W (bf16 in, fp32 acc), fused als/ald ----------------

template<int DOUT>
__global__ __launch_bounds__(256) void gemm_mfma(
    const unsigned short* __restrict__ xb,   // [n][128] bf16
    const unsigned short* __restrict__ Wt,   // [DOUT][128] bf16 (transposed W)
    const float* __restrict__ avs, const float* __restrict__ avd,
    unsigned* __restrict__ hb,               // [n][DOUT/2] packed bf16x2
    float* __restrict__ als, float* __restrict__ ald, int n) {
    constexpr int NT = DOUT / 16;
    int w = threadIdx.x >> 6, l = threadIdx.x & 63;
    int lc = l & 15, lg = l >> 4;
    int n0 = blockIdx.x * 64 + w * 16;
    int nrow = min(n0 + lc, n - 1);
    f32x4 acc[NT];
#pragma unroll
    for (int ct = 0; ct < NT; ct++) acc[ct] = (f32x4){0.f, 0.f, 0.f, 0.f};
    const unsigned short* xrow = xb + (size_t)nrow * 128 + lg * 8;
#pragma unroll
    for (int kb = 0; kb < 128; kb += 32) {
        short8 xf = *(const short8*)(xrow + kb);
#pragma unroll
        for (int ct = 0; ct < NT; ct++) {
            short8 wf = *(const short8*)(Wt + (size_t)(ct * 16 + lc) * 128 + kb + lg * 8);
            acc[ct] = __builtin_amdgcn_mfma_f32_16x16x32_bf16(wf, xf, acc[ct], 0, 0, 0);
        }
    }
    int node = n0 + lc;
    bool ok = node < n;
    float ps = 0.f, pd = 0.f;
#pragma unroll
    for (int ct = 0; ct < NT; ct++) {
        int cb = ct * 16 + lg * 4;
#pragma unroll
        for (int j = 0; j < 4; j++) { ps += acc[ct][j] * avs[cb + j]; pd += acc[ct][j] * avd[cb + j]; }
        if (ok) {
            uint2 v;
            v.x = (unsigned)f2bf(acc[ct][0]) | ((unsigned)f2bf(acc[ct][1]) << 16);
            v.y = (unsigned)f2bf(acc[ct][2]) | ((unsigned)f2bf(acc[ct][3]) << 16);
            *(uint2*)&hb[(size_t)node * (DOUT / 2) + ct * 8 + lg * 2] = v;
        }
    }
    ps += __shfl_xor(ps, 16); ps += __shfl_xor(ps, 32);
    pd += __shfl_xor(pd, 16); pd += __shfl_xor(pd, 32);
    if (ok && lg == 0) { als[node] = ps; ald[node] = pd; }
}

// ---------------- layer 1: DIN=7 -> DOUT=128 (fp32 math, bf16 h out) ----------------

__global__ __launch_bounds__(256) void linear_att_l1(
    const float* __restrict__ x, const float* __restrict__ W,
    const float* __restrict__ avs, const float* __restrict__ avd,
    unsigned* __restrict__ hb, float* __restrict__ als, float* __restrict__ ald, int n) {
    __shared__ float Wl[7 * 128];
    __shared__ float xsh[32][8];
    int tid = threadIdx.x;
    for (int i = tid; i < 7 * 128; i += 256) Wl[i] = W[i];
    int nodeBase = blockIdx.x * 32;
    if (tid < 224) {
        int nd = tid / 7, k = tid % 7;
        int g = min(nodeBase + nd, n - 1);
        xsh[nd][k] = x[(size_t)g * 7 + k];
    }
    __syncthreads();
    int nl = tid >> 3;
    int og = (tid & 7) * 16;
    int g = nodeBase + nl;
    float acc[16];
#pragma unroll
    for (int o = 0; o < 16; o++) acc[o] = 0.f;
#pragma unroll
    for (int k = 0; k < 7; k++) {
        float xv = xsh[nl][k];
#pragma unroll
        for (int o = 0; o < 16; o++) acc[o] += xv * Wl[k * 128 + og + o];
    }
    if (g < n) {
        unsigned pk[8];
#pragma unroll
        for (int o = 0; o < 16; o += 2)
            pk[o >> 1] = (unsigned)f2bf(acc[o]) | ((unsigned)f2bf(acc[o + 1]) << 16);
        uint4 v0, v1;
        v0.x = pk[0]; v0.y = pk[1]; v0.z = pk[2]; v0.w = pk[3];
        v1.x = pk[4]; v1.y = pk[5]; v1.z = pk[6]; v1.w = pk[7];
        *(uint4*)&hb[(size_t)g * 64 + (og >> 1)] = v0;
        *(uint4*)&hb[(size_t)g * 64 + (og >> 1) + 4] = v1;
        float ps = 0.f, pd = 0.f;
#pragma unroll
        for (int o = 0; o < 16; o++) { ps += acc[o] * avs[og + o]; pd += acc[o] * avd[og + o]; }
#pragma unroll
        for (int off = 1; off < 8; off <<= 1) { ps += __shfl_xor(ps, off); pd += __shfl_xor(pd, off); }
        if ((tid & 7) == 0) { als[g] = ps; ald[g] = pd; }
    }
}

// ---------------- softmax-weighted aggregation v5 ----------------
// One wave per node. Lane = (edge-of-group, 16B slice). Depth-4 chunked pipeline:
// 4 groups' (off,alpha) broadcasts, then 4 independent uint4 loads, then FMAs.

template<int DOUT, bool OBF>
__global__ __launch_bounds__(64) void gat_agg5(
    const int* __restrict__ rowptr, const int* __restrict__ csr,
    const float* __restrict__ als, const float* __restrict__ ald,
    const unsigned char* __restrict__ hbB, const float* __restrict__ bias,
    float* __restrict__ xout, int n) {
    constexpr int ROWB = DOUT * 2;   // h row bytes
    constexpr int LPE  = ROWB / 16;  // lanes per edge (16-B slices): 16 or 8
    constexpr int EPG  = 64 / LPE;   // edges per group: 4 or 8
    int lane = threadIdx.x;
    int node = blockIdx.x;
    if (node >= n) return;
    int beg = rowptr[node], end = rowptr[node + 1];
    int deg = end - beg;
    float adi = ald[node];

    // ---- pass A: softmax stats (max-butterfly, exp, sum-butterfly) ----
    float e0 = -INFINITY, mloc = -INFINITY;
    int src0 = node;
    {
        int idx = beg + lane;
        if (idx < end) {
            int src = csr[idx];
            float e = als[src] + adi;
            e = (e > 0.f) ? e : 0.2f * e;   // leaky_relu 0.2
            e0 = e; mloc = e; src0 = src;
            for (idx += 64; idx < end; idx += 64) {   // rare deg>64
                src = csr[idx];
                e = als[src] + adi;
                e = (e > 0.f) ? e : 0.2f * e;
                mloc = fmaxf(mloc, e);
            }
        }
    }
#pragma unroll
    for (int o = 1; o < 64; o <<= 1) mloc = fmaxf(mloc, __shfl_xor(mloc, o));
    float m = mloc;
    float p0 = expf(e0 - m);   // 0 for idle lanes (e0 = -inf)
    float sloc = p0;
    if (deg > 64) {
        for (int idx = beg + lane + 64; idx < end; idx += 64) {
            int src = csr[idx];
            float e = als[src] + adi;
            e = (e > 0.f) ? e : 0.2f * e;
            sloc += expf(e - m);
        }
    }
    float s = sloc;
#pragma unroll
    for (int o = 1; o < 64; o <<= 1) s += __shfl_xor(s, o);
    float inv_den = 1.f / s;

    // ---- pass B: depth-4 chunked 16-B slice gather ----
    int eSel = lane / LPE;
    const unsigned char* hbs = hbB + (lane % LPE) * 16;
    unsigned ownOff = (unsigned)node * ROWB;

    float acc[8];
#pragma unroll
    for (int i = 0; i < 8; i++) acc[i] = 0.f;

    for (int win = 0; win < deg; win += 64) {
        float alphaL; unsigned offL;
        if (win == 0) {
            alphaL = p0 * inv_den;
            offL = (beg + lane < end) ? (unsigned)src0 * ROWB : ownOff;
        } else {   // rare deg>64 windows
            int idx = beg + win + lane;
            if (idx < end) {
                int src = csr[idx];
                float e = als[src] + adi;
                e = (e > 0.f) ? e : 0.2f * e;
                alphaL = expf(e - m) * inv_den;
                offL = (unsigned)src * ROWB;
            } else { alphaL = 0.f; offL = ownOff; }
        }
        int limW = min(deg - win, 64);
        int nG = (limW + EPG - 1) / EPG;
        int nGr = (nG + 3) & ~3;  // round to 4; slots stay < 64 (padded lanes: alpha=0)
        for (int g = 0; g < nGr; g += 4) {
            unsigned off_[4]; float a_[4]; uint4 v_[4];
#pragma unroll
            for (int j = 0; j < 4; j++) {
                int slot = (g + j) * EPG + eSel;
                off_[j] = (unsigned)__shfl((int)offL, slot);
                a_[j]   = __shfl(alphaL, slot);
            }
#pragma unroll
            for (int j = 0; j < 4; j++) v_[j] = *(const uint4*)(hbs + off_[j]);
#pragma unroll
            for (int j = 0; j < 4; j++) {
                acc[0] += a_[j] * blo(v_[j].x); acc[1] += a_[j] * bhi(v_[j].x);
                acc[2] += a_[j] * blo(v_[j].y); acc[3] += a_[j] * bhi(v_[j].y);
                acc[4] += a_[j] * blo(v_[j].z); acc[5] += a_[j] * bhi(v_[j].z);
                acc[6] += a_[j] * blo(v_[j].w); acc[7] += a_[j] * bhi(v_[j].w);
            }
        }
    }

    // reduce edge-substreams (lanes with same slice index)
#pragma unroll
    for (int o = LPE; o < 64; o <<= 1) {
#pragma unroll
        for (int i = 0; i < 8; i++) acc[i] += __shfl_xor(acc[i], o);
    }

    if (lane < LPE) {
        int c0 = lane * 8;
        float v[8];
#pragma unroll
        for (int i = 0; i < 8; i++) {
            float t = acc[i] + bias[c0 + i];
            v[i] = (t > 0.f) ? t : expm1f(t);   // jax.nn.elu
        }
        if constexpr (OBF) {
            uint4 pk;
            pk.x = (unsigned)f2bf(v[0]) | ((unsigned)f2bf(v[1]) << 16);
            pk.y = (unsigned)f2bf(v[2]) | ((unsigned)f2bf(v[3]) << 16);
            pk.z = (unsigned)f2bf(v[4]) | ((unsigned)f2bf(v[5]) << 16);
            pk.w = (unsigned)f2bf(v[6]) | ((unsigned)f2bf(v[7]) << 16);
            *(uint4*)((unsigned*)xout + (size_t)node * (DOUT / 2) + lane * 4) = pk;
        } else {
            float4 f0, f1;
            f0.x = v[0]; f0.y = v[1]; f0.z = v[2]; f0.w = v[3];
            f1.x = v[4]; f1.y = v[5]; f1.z = v[6]; f1.w = v[7];
            *(float4*)&xout[(size_t)node * DOUT + c0] = f0;
            *(float4*)&xout[(size_t)node * DOUT + c0 + 4] = f1;
        }
    }
}

// ---------------- pool (mean over batch segment) + concat + final linear ----------------

__global__ __launch_bounds__(64) void pool_final_kernel(
    const float* __restrict__ x, const int* __restrict__ batch,
    const float* __restrict__ xnorm, const float* __restrict__ linW,
    const float* __restrict__ linb, float* __restrict__ out, int n) {
    int g = blockIdx.x, t = threadIdx.x;
    int lo = lowerBound(batch, n, g);
    int hi = lowerBound(batch, n, g + 1);
    float sum = 0.f;
    for (int i = lo; i < hi; i++) sum += x[(size_t)i * 64 + t];
    float cnt = (float)(hi - lo);
    float mean = sum / fmaxf(cnt, 1.f);
    __shared__ float gv[80];
    gv[t] = mean;
    if (t < 16) gv[64 + t] = xnorm[g * 16 + t];
    __syncthreads();
    float acc = linb[t];
#pragma unroll
    for (int k = 0; k < 80; k++) acc += gv[k] * linW[k * 64 + t];
    out[(size_t)g * 64 + t] = acc;
}

// ---------------- launch ----------------

extern "C" void kernel_launch(void* const* d_in, const int* in_sizes, int n_in,
                              void* d_out, int out_size, void* d_ws, size_t ws_size,
                              hipStream_t stream) {
    const float* x1  = (const float*)d_in[0];
    const float* x2  = (const float*)d_in[1];
    const int*   ei1 = (const int*)d_in[2];
    const int*   ei2 = (const int*)d_in[3];
    const int*   batch = (const int*)d_in[4];
    const float* xn1 = (const float*)d_in[6];
    const float* xn2 = (const float*)d_in[7];
    const float* W1 = (const float*)d_in[8];
    const float* as1 = (const float*)d_in[9];
    const float* ad1 = (const float*)d_in[10];
    const float* b1 = (const float*)d_in[11];
    const float* W2 = (const float*)d_in[12];
    const float* as2 = (const float*)d_in[13];
    const float* ad2 = (const float*)d_in[14];
    const float* b2 = (const float*)d_in[15];
    const float* W3 = (const float*)d_in[16];
    const float* as3 = (const float*)d_in[17];
    const float* ad3 = (const float*)d_in[18];
    const float* b3 = (const float*)d_in[19];
    const float* linW = (const float*)d_in[20];
    const float* linb = (const float*)d_in[21];
    float* out = (float*)d_out;

    char* ws = (char*)d_ws;
    size_t off = 0;
    auto alloc = [&](size_t bytes) -> void* {
        void* p = ws + off;
        off += (bytes + 255) & ~(size_t)255;
        return p;
    };
    int* rowptr    = (int*)alloc((N_NODES_C + 1) * sizeof(int));
    int* csr       = (int*)alloc((size_t)(N_EDGES_C + N_NODES_C) * sizeof(int));
    float* als     = (float*)alloc(N_NODES_C * sizeof(float));
    float* ald     = (float*)alloc(N_NODES_C * sizeof(float));
    int* bucketCnt = (int*)alloc(NBUK * sizeof(int));
    int* bucketPtr = (int*)alloc((NBUK + 1) * sizeof(int));
    int* bucketCur = (int*)alloc(NBUK * sizeof(int));
    unsigned short* Wt2 = (unsigned short*)alloc(128 * 128 * sizeof(unsigned short));
    unsigned short* Wt3 = (unsigned short*)alloc(64 * 128 * sizeof(unsigned short));
    float* bufX    = (float*)alloc((size_t)N_NODES_C * 64 * sizeof(float));        // fp32 final agg out
    unsigned* hb   = (unsigned*)alloc((size_t)N_NODES_C * 64 * sizeof(unsigned));  // bf16x2 h
    unsigned short* xbb = (unsigned short*)alloc((size_t)N_NODES_C * 128 * sizeof(unsigned short)); // bf16 x
    unsigned* bucketBuf = (unsigned*)bufX;  // aliased: lifetimes don't overlap
    (void)ws_size; (void)in_sizes; (void)n_in; (void)out_size;

    const int GEMM_GRID = (N_NODES_C + 63) / 64;

    // one-time: W2/W3 -> bf16 transposed
    wt_conv_kernel<<<(128 * 128 + 255) / 256, 256, 0, stream>>>(W2, Wt2, 128, 128);
    wt_conv_kernel<<<(128 * 64 + 255) / 256, 256, 0, stream>>>(W3, Wt3, 128, 64);

    for (int br = 0; br < 2; br++) {
        const float* x  = (br == 0) ? x1 : x2;
        const int*   ei = (br == 0) ? ei1 : ei2;
        const float* xn = (br == 0) ? xn1 : xn2;
        float* o = out + (size_t)br * N_GRAPHS_C * 64;

        // CSR build (dst-sorted adjacency incl. self loops, dense writes)
        hipMemsetAsync(bucketCnt, 0, NBUK * sizeof(int), stream);
        bucket_count_kernel<<<1024, 256, 0, stream>>>(ei, bucketCnt, N_EDGES_C);
        bucket_scan_kernel<<<1, 512, 0, stream>>>(bucketCnt, bucketPtr, bucketCur);
        bucket_scatter_kernel<<<256, 256, 0, stream>>>(ei, bucketCur, bucketBuf, N_EDGES_C);
        csr_finalize_kernel<<<NBUK, 256, 0, stream>>>(bucketPtr, bucketBuf, rowptr, csr, N_NODES_C);

        // Layer 1: 7 -> 128
        linear_att_l1<<<(N_NODES_C + 31) / 32, 256, 0, stream>>>(x, W1, as1, ad1, hb, als, ald, N_NODES_C);
        gat_agg5<128, true><<<N_NODES_C, 64, 0, stream>>>(rowptr, csr, als, ald, (const unsigned char*)hb, b1, (float*)xbb, N_NODES_C);
        // Layer 2: 128 -> 128 (MFMA)
        gemm_mfma<128><<<GEMM_GRID, 256, 0, stream>>>(xbb, Wt2, as2, ad2, hb, als, ald, N_NODES_C);
        gat_agg5<128, true><<<N_NODES_C, 64, 0, stream>>>(rowptr, csr, als, ald, (const unsigned char*)hb, b2, (float*)xbb, N_NODES_C);
        // Layer 3: 128 -> 64 (MFMA)
        gemm_mfma<64><<<GEMM_GRID, 256, 0, stream>>>(xbb, Wt3, as3, ad3, hb, als, ald, N_NODES_C);
        gat_agg5<64, false><<<N_NODES_C, 64, 0, stream>>>(rowptr, csr, als, ald, (const unsigned char*)hb, b3, bufX, N_NODES_C);

        // mean pool + concat + linear head
        pool_final_kernel<<<N_GRAPHS_C, 64, 0, stream>>>(bufX, batch, xn, linW, linb, o, N_NODES_C);
    }
}